// Round 6
// baseline (558.365 us; speedup 1.0000x reference)
//
#include <hip/hip_runtime.h>
#include <stdint.h>

#define B_ 32
#define S_ 2048
#define D_ 64
#define LOG2E 1.4426950408889634f

typedef __attribute__((ext_vector_type(8))) short short8v;
typedef __attribute__((ext_vector_type(4))) short short4v;
typedef __attribute__((ext_vector_type(4))) float f32x4;
typedef __attribute__((ext_vector_type(4))) float float4v;
typedef __attribute__((ext_vector_type(4))) int int4v;

// round-to-nearest-even fp32 -> bf16 (raw bits in short)
static __device__ inline short f2bf(float f){
  uint32_t u = __builtin_bit_cast(uint32_t, f);
  uint32_t r = (u + 0x7fffu + ((u >> 16) & 1u)) >> 16;
  return (short)(uint16_t)r;
}

// ---- kernel 0a: q (pre-scaled by 1/8) and k -> bf16 row-major ----
__global__ __launch_bounds__(256) void cvt_qk(const float* __restrict__ q,
                                              const float* __restrict__ k,
                                              short* __restrict__ qb,
                                              short* __restrict__ kb){
  size_t i = ((size_t)blockIdx.x * 256 + threadIdx.x) * 4;
  float4v a = *(const float4v*)(q + i);
  float4v c = *(const float4v*)(k + i);
  short4v qa = { f2bf(a[0]*0.125f), f2bf(a[1]*0.125f), f2bf(a[2]*0.125f), f2bf(a[3]*0.125f) };
  short4v kc = { f2bf(c[0]), f2bf(c[1]), f2bf(c[2]), f2bf(c[3]) };
  *(short4v*)(qb + i) = qa;
  *(short4v*)(kb + i) = kc;
}

// ---- kernel 0b: v -> bf16 transposed per batch: vbT[b][d][s] ----
__global__ __launch_bounds__(256) void cvt_v(const float* __restrict__ v,
                                             short* __restrict__ vbT){
  __shared__ float tile[64][65];
  int b = blockIdx.y, st = blockIdx.x;
  int tid = threadIdx.x;
#pragma unroll
  for (int i = 0; i < 4; i++){
    int s = tid + i*256;                    // 1024 float4 slots = 64x64 floats
    int row = s >> 4, c4 = (s & 15) * 4;
    float4v t = *(const float4v*)(v + ((size_t)b*S_ + st*64 + row)*D_ + c4);
    tile[row][c4+0] = t[0]; tile[row][c4+1] = t[1];
    tile[row][c4+2] = t[2]; tile[row][c4+3] = t[3];
  }
  __syncthreads();
#pragma unroll
  for (int i = 0; i < 2; i++){
    int s = tid + i*256;                    // 512 out slots (64 d-rows x 8)
    int d = s >> 3, s8 = (s & 7) * 8;
    short8v o;
#pragma unroll
    for (int j = 0; j < 8; j++) o[j] = f2bf(tile[s8 + j][d]);
    *(short8v*)(vbT + ((size_t)b*D_ + d)*S_ + st*64 + s8) = o;
  }
}

// ---- main fused kernel: BARRIER-FREE wave-autonomous two-sweep attention ----
// 1 wave per workgroup (64 thr); wave owns 16 q rows; grid (qt=128, b=32).
// K/V MFMA fragments read directly from global (L2-resident per batch);
// LDS only for same-wave P-stash + packed-mask stash -> zero __syncthreads.
__global__ __launch_bounds__(64) void attn_fused(
    const short* __restrict__ qb, const short* __restrict__ kb,
    const short* __restrict__ vbT, const int* __restrict__ mask,
    float* __restrict__ outp, float* __restrict__ attn)
{
  __shared__ __align__(16) char lds[6*1024];
  char*     sP  = lds;                       // P tile: 16 rows x 128B (2KB)
  uint16_t* sMB = (uint16_t*)(lds + 2048);   // packed mask: 32 stages x 64 lanes (4KB)

  const int lane = threadIdx.x;    // 0..63 (one wave)
  const int lq   = lane & 15;      // q-row within wave tile / col idx
  const int g    = lane >> 4;      // 4 lane-groups

  const int b  = blockIdx.y;
  const int qt = blockIdx.x;
  const int q0 = qt*16;

  // Q B-fragments (lane holds Q[q0+lq][d = c*32 + g*8 + j]), q pre-scaled by 1/8
  const size_t qoff = ((size_t)b*S_ + q0 + lq) * D_;
  const short8v qf0 = *(const short8v*)(qb + qoff + g*8);
  const short8v qf1 = *(const short8v*)(qb + qoff + 32 + g*8);

  const short* kbb  = kb  + (size_t)b*S_*D_;   // batch K base (row-major [s][d])
  const short* vbb  = vbT + (size_t)b*D_*S_;   // batch V^T base ([d][s])
  const int*   mrow = mask + ((size_t)b*S_ + q0 + lq) * S_;

  float lrun = 0.f;

  // mask prefetch: stage-0 quads
  int4v mc[4], mn[4];
#pragma unroll
  for (int kkk = 0; kkk < 4; kkk++)
    mc[kkk] = *(const int4v*)(mrow + kkk*16 + g*4);

  // ========== sweep 1: row sum of exp (max-free; per-lane partial) ==========
  for (int st = 0; st < 32; ++st){
    const int ks = st*64;
    // issue next stage's mask loads (a barrier-free stage of compute hides them)
    const int nks = (st < 31) ? ks + 64 : 0;
#pragma unroll
    for (int kkk = 0; kkk < 4; kkk++)
      mn[kkk] = *(const int4v*)(mrow + nks + kkk*16 + g*4);

    uint32_t bits = 0;
#pragma unroll
    for (int kkk = 0; kkk < 4; kkk++){
      const int r = ks + kkk*16 + lq;
      short8v ka0 = *(const short8v*)(kbb + (size_t)r*D_ + g*8);
      short8v ka1 = *(const short8v*)(kbb + (size_t)r*D_ + 32 + g*8);
      f32x4 acc = {0.f,0.f,0.f,0.f};
      acc = __builtin_amdgcn_mfma_f32_16x16x32_bf16(ka0, qf0, acc, 0,0,0);
      acc = __builtin_amdgcn_mfma_f32_16x16x32_bf16(ka1, qf1, acc, 0,0,0);
      // lane holds S[q=lq][k = ks + kkk*16 + 4g + reg]
      uint32_t nib = (mc[kkk][0] ? 1u : 0u) | (mc[kkk][1] ? 2u : 0u)
                   | (mc[kkk][2] ? 4u : 0u) | (mc[kkk][3] ? 8u : 0u);
      bits |= nib << (kkk*4);
      float e0 = (nib & 1u) ? 0.f : exp2f(acc[0]*LOG2E);
      float e1 = (nib & 2u) ? 0.f : exp2f(acc[1]*LOG2E);
      float e2 = (nib & 4u) ? 0.f : exp2f(acc[2]*LOG2E);
      float e3 = (nib & 8u) ? 0.f : exp2f(acc[3]*LOG2E);
      lrun += (e0 + e1) + (e2 + e3);
    }
    sMB[st*64 + lane] = (uint16_t)bits;
#pragma unroll
    for (int kkk = 0; kkk < 4; kkk++) mc[kkk] = mn[kkk];
  }
  // cross-lane row sum: combine the 4 g-groups holding the same q-row
  lrun += __shfl_xor(lrun, 16, 64);
  lrun += __shfl_xor(lrun, 32, 64);
  const float invl = 1.0f / lrun;

  // ================= sweep 2: recompute, write attn, accumulate PV ==========
  f32x4 oacc[4];
#pragma unroll
  for (int n = 0; n < 4; n++) oacc[n] = (f32x4){0.f,0.f,0.f,0.f};

  for (int st = 0; st < 32; ++st){
    const int ks = st*64;
    const uint32_t bt = sMB[st*64 + lane];
#pragma unroll
    for (int c = 0; c < 2; c++){            // two k32 chunks per stage
#pragma unroll
      for (int t2 = 0; t2 < 2; t2++){       // two 16-k tiles per chunk
        const int kkk = c*2 + t2;
        const int r = ks + kkk*16 + lq;
        short8v ka0 = *(const short8v*)(kbb + (size_t)r*D_ + g*8);
        short8v ka1 = *(const short8v*)(kbb + (size_t)r*D_ + 32 + g*8);
        f32x4 acc = {0.f,0.f,0.f,0.f};
        acc = __builtin_amdgcn_mfma_f32_16x16x32_bf16(ka0, qf0, acc, 0,0,0);
        acc = __builtin_amdgcn_mfma_f32_16x16x32_bf16(ka1, qf1, acc, 0,0,0);
        uint32_t m4 = (bt >> (kkk*4)) & 15u;
        float p0 = (m4 & 1u) ? 0.f : exp2f(acc[0]*LOG2E) * invl;
        float p1 = (m4 & 2u) ? 0.f : exp2f(acc[1]*LOG2E) * invl;
        float p2 = (m4 & 4u) ? 0.f : exp2f(acc[2]*LOG2E) * invl;
        float p3 = (m4 & 8u) ? 0.f : exp2f(acc[3]*LOG2E) * invl;
        // write normalized attn (float4, 64B-contiguous per 4 lane-group)
        f32x4 stv = { p0, p1, p2, p3 };
        *(f32x4*)(attn + ((size_t)b*S_ + q0 + lq)*S_ + ks + kkk*16 + g*4) = stv;
        // stash P (bf16) for the PV A-fragment (same-wave LDS, no barrier)
        short4v pb = { f2bf(p0), f2bf(p1), f2bf(p2), f2bf(p3) };
        *(short4v*)(sP + lq*128 + ((t2*32 + g*8) ^ ((lq & 7) << 4))) = pb;
      }
      // PV: A = P[16q][32k] fragment from LDS, B = V chunk direct from global
      short8v pf = *(const short8v*)(sP + lq*128 + ((g*16) ^ ((lq & 7) << 4)));
#pragma unroll
      for (int n = 0; n < 4; n++){
        const int dr = lq + 16*n;
        short8v vf = *(const short8v*)(vbb + (size_t)dr*S_ + ks + c*32 + g*8);
        oacc[n] = __builtin_amdgcn_mfma_f32_16x16x32_bf16(pf, vf, oacc[n], 0,0,0);
      }
    }
  }

  // epilogue: O[q = q0 + 4g + reg][d = lq + 16n]
#pragma unroll
  for (int n = 0; n < 4; n++){
#pragma unroll
    for (int r2 = 0; r2 < 4; r2++){
      outp[((size_t)b*S_ + q0 + 4*g + r2)*D_ + lq + 16*n] = oacc[n][r2];
    }
  }
}

extern "C" void kernel_launch(void* const* d_in, const int* in_sizes, int n_in,
                              void* d_out, int out_size, void* d_ws, size_t ws_size,
                              hipStream_t stream) {
  (void)in_sizes; (void)n_in; (void)out_size; (void)ws_size;
  const float* q    = (const float*)d_in[0];
  const float* k    = (const float*)d_in[1];
  const float* v    = (const float*)d_in[2];
  const int*   mask = (const int*)d_in[3];   // bool -> int32 per harness convention

  float* outp = (float*)d_out;
  float* attn = outp + (size_t)B_*S_*D_;    // outputs concatenated: output, attn

  short* qbuf = (short*)d_ws;               // 3 x 8.39MB bf16 scratch
  short* kbuf = qbuf + (size_t)B_*S_*D_;
  short* vbT  = kbuf + (size_t)B_*S_*D_;

  cvt_qk<<<4096, 256, 0, stream>>>(q, k, qbuf, kbuf);
  cvt_v<<<dim3(32, 32), 256, 0, stream>>>(v, vbT);
  attn_fused<<<dim3(128, 32), 64, 0, stream>>>(qbuf, kbuf, vbT, mask, outp, attn);
}

// Round 7
// 366.009 us; speedup vs baseline: 1.5255x; 1.5255x over previous
//
#include <hip/hip_runtime.h>
#include <stdint.h>

#define B_ 32
#define S_ 2048
#define D_ 64
#define LOG2E 1.4426950408889634f

typedef __attribute__((ext_vector_type(8))) short short8v;
typedef __attribute__((ext_vector_type(4))) short short4v;
typedef __attribute__((ext_vector_type(4))) float f32x4;
typedef __attribute__((ext_vector_type(4))) float float4v;
typedef __attribute__((ext_vector_type(4))) int int4v;

// round-to-nearest-even fp32 -> bf16 (raw bits in short)
static __device__ inline short f2bf(float f){
  uint32_t u = __builtin_bit_cast(uint32_t, f);
  uint32_t r = (u + 0x7fffu + ((u >> 16) & 1u)) >> 16;
  return (short)(uint16_t)r;
}

// async global->LDS DMA, 16B per lane; dest = wave-uniform base + lane*16
static __device__ inline void gl16(const void* g, void* l){
  __builtin_amdgcn_global_load_lds(
      (const __attribute__((address_space(1))) void*)g,
      (__attribute__((address_space(3))) void*)l, 16, 0, 0);
}

// ---- kernel 0a: q (pre-scaled by 1/8) and k -> bf16 row-major ----
__global__ __launch_bounds__(256) void cvt_qk(const float* __restrict__ q,
                                              const float* __restrict__ k,
                                              short* __restrict__ qb,
                                              short* __restrict__ kb){
  size_t i = ((size_t)blockIdx.x * 256 + threadIdx.x) * 4;
  float4v a = *(const float4v*)(q + i);
  float4v c = *(const float4v*)(k + i);
  short4v qa = { f2bf(a[0]*0.125f), f2bf(a[1]*0.125f), f2bf(a[2]*0.125f), f2bf(a[3]*0.125f) };
  short4v kc = { f2bf(c[0]), f2bf(c[1]), f2bf(c[2]), f2bf(c[3]) };
  *(short4v*)(qb + i) = qa;
  *(short4v*)(kb + i) = kc;
}

// ---- kernel 0b: v -> bf16 transposed per batch: vbT[b][d][s] ----
__global__ __launch_bounds__(256) void cvt_v(const float* __restrict__ v,
                                             short* __restrict__ vbT){
  __shared__ float tile[64][65];
  int b = blockIdx.y, st = blockIdx.x;
  int tid = threadIdx.x;
#pragma unroll
  for (int i = 0; i < 4; i++){
    int s = tid + i*256;
    int row = s >> 4, c4 = (s & 15) * 4;
    float4v t = *(const float4v*)(v + ((size_t)b*S_ + st*64 + row)*D_ + c4);
    tile[row][c4+0] = t[0]; tile[row][c4+1] = t[1];
    tile[row][c4+2] = t[2]; tile[row][c4+3] = t[3];
  }
  __syncthreads();
#pragma unroll
  for (int i = 0; i < 2; i++){
    int s = tid + i*256;
    int d = s >> 3, s8 = (s & 7) * 8;
    short8v o;
#pragma unroll
    for (int j = 0; j < 8; j++) o[j] = f2bf(tile[s8 + j][d]);
    *(short8v*)(vbT + ((size_t)b*D_ + d)*S_ + st*64 + s8) = o;
  }
}

// ---- main fused kernel: DMA-pipelined two-sweep max-free masked softmax + PV
// 512 thr (8 waves), 128 q-rows/block, grid (16,32). All staging via
// global_load_lds double-buffer; raw s_barrier + counted vmcnt (no drains).
// LDS map (144KB): K dbuf 2x8K @0 | V dbuf 2x8K @16K | mask dbuf 2x32K @32K
//                  P 8x2K @96K | packed bits 8x4K @112K
#define WAIT0 asm volatile("s_waitcnt vmcnt(0)" ::: "memory")
#define WAIT4 asm volatile("s_waitcnt vmcnt(4)" ::: "memory")
#define BAR   __builtin_amdgcn_s_barrier()

__global__ __launch_bounds__(512) void attn_fused(
    const short* __restrict__ qb, const short* __restrict__ kb,
    const short* __restrict__ vbT, const int* __restrict__ mask,
    float* __restrict__ outp, float* __restrict__ attn)
{
  __shared__ __align__(16) char lds[147456];
  const int tid  = threadIdx.x;
  const int w    = tid >> 6;
  const int lane = tid & 63;
  const int lq   = lane & 15;
  const int g    = lane >> 4;

  const int b   = blockIdx.y;
  const int q0b = blockIdx.x * 128;
  const int q0  = q0b + w*16;

  const short* kbb = kb  + (size_t)b*S_*D_;
  const short* vbb = vbT + (size_t)b*D_*S_;
  const int*   mkb = mask + ((size_t)b*S_ + q0b)*S_;

  // per-thread DMA source pointers (source pre-swizzled; LDS dest linear)
  const int krow = tid >> 3;
  const int kc   = (((tid & 7) ^ (krow & 7)) << 3);      // shorts within row
  const short* kSrc = kbb + (size_t)krow*D_ + kc;        // + ks*D_ per stage
  const short* vSrc = vbb + (size_t)krow*S_ + kc;        // + ks per stage
  const int rr0 = (0*512 + tid) >> 4, cc0 = ((((0*512+tid)&15) ^ (rr0&7)) << 2);
  const int rr1 = (1*512 + tid) >> 4, cc1 = ((((1*512+tid)&15) ^ (rr1&7)) << 2);
  const int rr2 = (2*512 + tid) >> 4, cc2 = ((((2*512+tid)&15) ^ (rr2&7)) << 2);
  const int rr3 = (3*512 + tid) >> 4, cc3 = ((((3*512+tid)&15) ^ (rr3&7)) << 2);
  const int* mSrc0 = mkb + (size_t)rr0*S_ + cc0;
  const int* mSrc1 = mkb + (size_t)rr1*S_ + cc1;
  const int* mSrc2 = mkb + (size_t)rr2*S_ + cc2;
  const int* mSrc3 = mkb + (size_t)rr3*S_ + cc3;
  const int ldsMW = w << 10;   // per-wave 1KB slice of each DMA issue

  // Q B-fragments (q pre-scaled by 1/8)
  const size_t qoff = ((size_t)b*S_ + q0 + lq) * D_;
  const short8v qf0 = *(const short8v*)(qb + qoff + g*8);
  const short8v qf1 = *(const short8v*)(qb + qoff + 32 + g*8);

  char*     sP  = lds + 98304 + (w << 11);               // 16 rows x 128B
  uint16_t* sMB = (uint16_t*)(lds + 114688 + (w << 12)); // 32 stages x 64 lanes

#define ISSUE1(s) do{ const int _b=(s)&1; const size_t _ks=(size_t)((s)<<6); \
    gl16(kSrc + _ks*D_,  lds + (_b<<13) + ldsMW); \
    gl16(mSrc0 + _ks, lds + 32768 + (_b<<15) +     0 + ldsMW); \
    gl16(mSrc1 + _ks, lds + 32768 + (_b<<15) +  8192 + ldsMW); \
    gl16(mSrc2 + _ks, lds + 32768 + (_b<<15) + 16384 + ldsMW); \
    gl16(mSrc3 + _ks, lds + 32768 + (_b<<15) + 24576 + ldsMW); }while(0)

#define ISSUE2(s) do{ const int _b=(s)&1; const size_t _ks=(size_t)((s)<<6); \
    gl16(kSrc + _ks*D_, lds + (_b<<13) + ldsMW); \
    gl16(vSrc + _ks,    lds + 16384 + (_b<<13) + ldsMW); }while(0)

  float lrun = 0.f;

  // ========== sweep 1: row sum of exp (max-free), pack mask bits ==========
  ISSUE1(0);
  for (int st = 0; st < 32; ++st){
    WAIT0; BAR;
    if (st < 31) ISSUE1(st+1);
    const char* sKc = lds + ((st&1) << 13);
    const char* sMc = lds + 32768 + ((st&1) << 15);
    uint32_t bits = 0;
#pragma unroll
    for (int kkk = 0; kkk < 4; kkk++){
      const int r = (kkk<<4) + lq;
      short8v ka0 = *(const short8v*)(sKc + r*128 + (( g*16     ) ^ ((r & 7) << 4)));
      short8v ka1 = *(const short8v*)(sKc + r*128 + ((64 + g*16 ) ^ ((r & 7) << 4)));
      f32x4 acc = {0.f,0.f,0.f,0.f};
      acc = __builtin_amdgcn_mfma_f32_16x16x32_bf16(ka0, qf0, acc, 0,0,0);
      acc = __builtin_amdgcn_mfma_f32_16x16x32_bf16(ka1, qf1, acc, 0,0,0);
      int4v mu = *(const int4v*)(sMc + (w*16 + lq)*256 + ((((kkk<<2)+g) ^ (lq & 7)) << 4));
      uint32_t nib = (mu[0]?1u:0u)|(mu[1]?2u:0u)|(mu[2]?4u:0u)|(mu[3]?8u:0u);
      bits |= nib << (kkk*4);
      float e0 = (nib & 1u) ? 0.f : exp2f(acc[0]*LOG2E);
      float e1 = (nib & 2u) ? 0.f : exp2f(acc[1]*LOG2E);
      float e2 = (nib & 4u) ? 0.f : exp2f(acc[2]*LOG2E);
      float e3 = (nib & 8u) ? 0.f : exp2f(acc[3]*LOG2E);
      lrun += (e0 + e1) + (e2 + e3);
    }
    sMB[(st<<6) + lane] = (uint16_t)bits;
  }
  lrun += __shfl_xor(lrun, 16, 64);
  lrun += __shfl_xor(lrun, 32, 64);
  const float invl = 1.0f / lrun;

  // ========== sweep 2: recompute, write attn, accumulate PV ==========
  f32x4 oacc[4];
#pragma unroll
  for (int n = 0; n < 4; n++) oacc[n] = (f32x4){0.f,0.f,0.f,0.f};

  auto compute2 = [&](int st){
    const int ks = st << 6;
    const char* sKc = lds + ((st&1) << 13);
    const char* sVc = lds + 16384 + ((st&1) << 13);
    const uint32_t bt = sMB[(st<<6) + lane];
#pragma unroll
    for (int c = 0; c < 2; c++){
#pragma unroll
      for (int t2 = 0; t2 < 2; t2++){
        const int kkk = c*2 + t2;
        const int r = (kkk<<4) + lq;
        short8v ka0 = *(const short8v*)(sKc + r*128 + (( g*16     ) ^ ((r & 7) << 4)));
        short8v ka1 = *(const short8v*)(sKc + r*128 + ((64 + g*16 ) ^ ((r & 7) << 4)));
        f32x4 acc = {0.f,0.f,0.f,0.f};
        acc = __builtin_amdgcn_mfma_f32_16x16x32_bf16(ka0, qf0, acc, 0,0,0);
        acc = __builtin_amdgcn_mfma_f32_16x16x32_bf16(ka1, qf1, acc, 0,0,0);
        uint32_t m4 = (bt >> (kkk*4)) & 15u;
        float p0 = (m4 & 1u) ? 0.f : exp2f(acc[0]*LOG2E) * invl;
        float p1 = (m4 & 2u) ? 0.f : exp2f(acc[1]*LOG2E) * invl;
        float p2 = (m4 & 4u) ? 0.f : exp2f(acc[2]*LOG2E) * invl;
        float p3 = (m4 & 8u) ? 0.f : exp2f(acc[3]*LOG2E) * invl;
        f32x4 stv = { p0, p1, p2, p3 };
        *(f32x4*)(attn + ((size_t)b*S_ + q0 + lq)*S_ + ks + kkk*16 + g*4) = stv;
        short4v pb = { f2bf(p0), f2bf(p1), f2bf(p2), f2bf(p3) };
        *(short4v*)(sP + lq*128 + ((t2*32 + g*8) ^ ((lq & 7) << 4))) = pb;
      }
      short8v pf = *(const short8v*)(sP + lq*128 + ((g*16) ^ ((lq & 7) << 4)));
#pragma unroll
      for (int n = 0; n < 4; n++){
        const int dr = lq + 16*n;
        short8v vf = *(const short8v*)(sVc + dr*128 + ((c*64 + g*16) ^ ((dr & 7) << 4)));
        oacc[n] = __builtin_amdgcn_mfma_f32_16x16x32_bf16(pf, vf, oacc[n], 0,0,0);
      }
    }
  };

  ISSUE2(0);
  WAIT0; BAR;            // stage-0 landed (no stores outstanding yet)
  ISSUE2(1);
  compute2(0);
  for (int st = 1; st < 32; ++st){
    WAIT4; BAR;          // allow the 4 attn-store instrs of st-1 to stay in flight
    if (st < 31) ISSUE2(st+1);
    compute2(st);
  }

  // epilogue: O[q = q0 + 4g + reg][d = lq + 16n]
#pragma unroll
  for (int n = 0; n < 4; n++){
#pragma unroll
    for (int r2 = 0; r2 < 4; r2++){
      outp[((size_t)b*S_ + q0 + 4*g + r2)*D_ + lq + 16*n] = oacc[n][r2];
    }
  }
#undef ISSUE1
#undef ISSUE2
}

extern "C" void kernel_launch(void* const* d_in, const int* in_sizes, int n_in,
                              void* d_out, int out_size, void* d_ws, size_t ws_size,
                              hipStream_t stream) {
  (void)in_sizes; (void)n_in; (void)out_size; (void)ws_size;
  const float* q    = (const float*)d_in[0];
  const float* k    = (const float*)d_in[1];
  const float* v    = (const float*)d_in[2];
  const int*   mask = (const int*)d_in[3];   // bool -> int32 per harness convention

  float* outp = (float*)d_out;
  float* attn = outp + (size_t)B_*S_*D_;     // outputs concatenated: output, attn

  short* qbuf = (short*)d_ws;                // 3 x 8.39MB bf16 scratch
  short* kbuf = qbuf + (size_t)B_*S_*D_;
  short* vbT  = kbuf + (size_t)B_*S_*D_;

  cvt_qk<<<4096, 256, 0, stream>>>(q, k, qbuf, kbuf);
  cvt_v<<<dim3(32, 32), 256, 0, stream>>>(v, vbT);
  attn_fused<<<dim3(16, 32), 512, 0, stream>>>(qbuf, kbuf, vbT, mask, outp, attn);
}

// Round 8
// 336.500 us; speedup vs baseline: 1.6593x; 1.0877x over previous
//
#include <hip/hip_runtime.h>
#include <stdint.h>

#define B_ 32
#define S_ 2048
#define D_ 64
#define LOG2E 1.4426950408889634f

typedef __attribute__((ext_vector_type(8))) short short8v;
typedef __attribute__((ext_vector_type(4))) short short4v;
typedef __attribute__((ext_vector_type(4))) float f32x4;
typedef __attribute__((ext_vector_type(4))) float float4v;
typedef __attribute__((ext_vector_type(4))) int int4v;

// round-to-nearest-even fp32 -> bf16 (raw bits in short)
static __device__ inline short f2bf(float f){
  uint32_t u = __builtin_bit_cast(uint32_t, f);
  uint32_t r = (u + 0x7fffu + ((u >> 16) & 1u)) >> 16;
  return (short)(uint16_t)r;
}

// async global->LDS DMA, 16B per lane; dest = wave-uniform base + lane*16
static __device__ inline void gl16(const void* g, void* l){
  __builtin_amdgcn_global_load_lds(
      (const __attribute__((address_space(1))) void*)g,
      (__attribute__((address_space(3))) void*)l, 16, 0, 0);
}

// ---- kernel 0a: q (pre-scaled by 1/8) and k -> bf16 row-major ----
__global__ __launch_bounds__(256) void cvt_qk(const float* __restrict__ q,
                                              const float* __restrict__ k,
                                              short* __restrict__ qb,
                                              short* __restrict__ kb){
  size_t i = ((size_t)blockIdx.x * 256 + threadIdx.x) * 4;
  float4v a = *(const float4v*)(q + i);
  float4v c = *(const float4v*)(k + i);
  short4v qa = { f2bf(a[0]*0.125f), f2bf(a[1]*0.125f), f2bf(a[2]*0.125f), f2bf(a[3]*0.125f) };
  short4v kc = { f2bf(c[0]), f2bf(c[1]), f2bf(c[2]), f2bf(c[3]) };
  *(short4v*)(qb + i) = qa;
  *(short4v*)(kb + i) = kc;
}

// ---- kernel 0b: v -> bf16 transposed per batch: vbT[b][d][s] ----
__global__ __launch_bounds__(256) void cvt_v(const float* __restrict__ v,
                                             short* __restrict__ vbT){
  __shared__ float tile[64][65];
  int b = blockIdx.y, st = blockIdx.x;
  int tid = threadIdx.x;
#pragma unroll
  for (int i = 0; i < 4; i++){
    int s = tid + i*256;
    int row = s >> 4, c4 = (s & 15) * 4;
    float4v t = *(const float4v*)(v + ((size_t)b*S_ + st*64 + row)*D_ + c4);
    tile[row][c4+0] = t[0]; tile[row][c4+1] = t[1];
    tile[row][c4+2] = t[2]; tile[row][c4+3] = t[3];
  }
  __syncthreads();
#pragma unroll
  for (int i = 0; i < 2; i++){
    int s = tid + i*256;
    int d = s >> 3, s8 = (s & 7) * 8;
    short8v o;
#pragma unroll
    for (int j = 0; j < 8; j++) o[j] = f2bf(tile[s8 + j][d]);
    *(short8v*)(vbT + ((size_t)b*D_ + d)*S_ + st*64 + s8) = o;
  }
}

// ---- main fused kernel: DMA-pipelined two-sweep max-free masked softmax + PV
// 256 thr (4 waves), 64 q-rows/block, grid (32,32) => 2 blocks/CU (72KB LDS).
// LDS map: K dbuf 2x8K @0 | UNION @16K: s1 mask dbuf 2x16K / s2 V dbuf 2x8K
//          P 4x2K @48K | packed bits 4x4K @56K   (total 72KB)
#define WAIT0 asm volatile("s_waitcnt vmcnt(0)" ::: "memory")
#define WAIT4 asm volatile("s_waitcnt vmcnt(4)" ::: "memory")
#define BAR   __builtin_amdgcn_s_barrier()

__global__ __launch_bounds__(256, 2) void attn_fused(
    const short* __restrict__ qb, const short* __restrict__ kb,
    const short* __restrict__ vbT, const int* __restrict__ mask,
    float* __restrict__ outp, float* __restrict__ attn)
{
  __shared__ __align__(16) char lds[73728];
  const int tid  = threadIdx.x;
  const int w    = tid >> 6;
  const int lane = tid & 63;
  const int lq   = lane & 15;
  const int g    = lane >> 4;
  const int woff = w << 10;          // per-wave 1KB slice of each DMA issue

  const int b   = blockIdx.y;
  const int q0b = blockIdx.x * 64;
  const int q0  = q0b + w*16;

  const short* kbb = kb  + (size_t)b*S_*D_;
  const short* vbb = vbT + (size_t)b*D_*S_;
  const int*   mkb = mask + ((size_t)b*S_ + q0b)*S_;

  // K/V DMA source (2 issues x 256 thr x 16B = 8KB tile; src pre-swizzled)
  const int s0 = tid, s1 = 256 + tid;
  const int kr0 = s0 >> 3, kc0 = ((s0 & 7) ^ (kr0 & 7)) << 3;  // shorts
  const int kr1 = s1 >> 3, kc1 = ((s1 & 7) ^ (kr1 & 7)) << 3;
  const short* kSrc0 = kbb + (size_t)kr0*D_ + kc0;   // + ks*D_ per stage
  const short* kSrc1 = kbb + (size_t)kr1*D_ + kc1;
  const short* vSrc0 = vbb + (size_t)kr0*S_ + kc0;   // + ks per stage
  const short* vSrc1 = vbb + (size_t)kr1*S_ + kc1;

  // mask DMA source (4 issues x 256 thr x 16B = 16KB: 64 rows x 256B)
  const int m0 = 0*256 + tid, m1 = 1*256 + tid, m2 = 2*256 + tid, m3 = 3*256 + tid;
  const int mr0 = m0 >> 4, mc0 = ((m0 & 15) ^ (mr0 & 7)) << 2;  // ints
  const int mr1 = m1 >> 4, mc1 = ((m1 & 15) ^ (mr1 & 7)) << 2;
  const int mr2 = m2 >> 4, mc2 = ((m2 & 15) ^ (mr2 & 7)) << 2;
  const int mr3 = m3 >> 4, mc3 = ((m3 & 15) ^ (mr3 & 7)) << 2;
  const int* mSrc0 = mkb + (size_t)mr0*S_ + mc0;     // + ks per stage
  const int* mSrc1 = mkb + (size_t)mr1*S_ + mc1;
  const int* mSrc2 = mkb + (size_t)mr2*S_ + mc2;
  const int* mSrc3 = mkb + (size_t)mr3*S_ + mc3;

  // Q B-fragments (q pre-scaled by 1/8)
  const size_t qoff = ((size_t)b*S_ + q0 + lq) * D_;
  const short8v qf0 = *(const short8v*)(qb + qoff + g*8);
  const short8v qf1 = *(const short8v*)(qb + qoff + 32 + g*8);

  char*     sP  = lds + 49152 + (w << 11);              // 16 rows x 128B
  uint16_t* sMB = (uint16_t*)(lds + 57344) + (w << 11); // 32 st x 64 lanes

  auto ISSUE1 = [&](int s){
    const int b2 = s & 1; const size_t ks = (size_t)(s << 6);
    gl16(kSrc0 + ks*D_, lds + b2*8192 +    0 + woff);
    gl16(kSrc1 + ks*D_, lds + b2*8192 + 4096 + woff);
    gl16(mSrc0 + ks, lds + 16384 + b2*16384 +     0 + woff);
    gl16(mSrc1 + ks, lds + 16384 + b2*16384 +  4096 + woff);
    gl16(mSrc2 + ks, lds + 16384 + b2*16384 +  8192 + woff);
    gl16(mSrc3 + ks, lds + 16384 + b2*16384 + 12288 + woff);
  };
  auto ISSUE2 = [&](int s){
    const int b2 = s & 1; const size_t ks = (size_t)(s << 6);
    gl16(kSrc0 + ks*D_, lds + b2*8192 +    0 + woff);
    gl16(kSrc1 + ks*D_, lds + b2*8192 + 4096 + woff);
    gl16(vSrc0 + ks, lds + 16384 + b2*8192 +    0 + woff);
    gl16(vSrc1 + ks, lds + 16384 + b2*8192 + 4096 + woff);
  };

  float lrun = 0.f;

  // ========== sweep 1: row sum of exp (max-free), pack mask bits ==========
  ISSUE1(0);
  for (int st = 0; st < 32; ++st){
    WAIT0; BAR;
    if (st < 31) ISSUE1(st+1);
    const char* sKc = lds + ((st&1) << 13);
    const char* sMc = lds + 16384 + ((st&1) << 14);
    uint32_t bits = 0;
#pragma unroll
    for (int kkk = 0; kkk < 4; kkk++){
      const int r = (kkk<<4) + lq;
      short8v ka0 = *(const short8v*)(sKc + r*128 + (( g*16     ) ^ ((r & 7) << 4)));
      short8v ka1 = *(const short8v*)(sKc + r*128 + ((64 + g*16 ) ^ ((r & 7) << 4)));
      f32x4 acc = {0.f,0.f,0.f,0.f};
      acc = __builtin_amdgcn_mfma_f32_16x16x32_bf16(ka0, qf0, acc, 0,0,0);
      acc = __builtin_amdgcn_mfma_f32_16x16x32_bf16(ka1, qf1, acc, 0,0,0);
      int4v mu = *(const int4v*)(sMc + (w*16 + lq)*256 + ((((kkk<<2)+g) ^ (lq & 7)) << 4));
      uint32_t nib = (mu[0]?1u:0u)|(mu[1]?2u:0u)|(mu[2]?4u:0u)|(mu[3]?8u:0u);
      bits |= nib << (kkk*4);
      float e0 = (nib & 1u) ? 0.f : exp2f(acc[0]*LOG2E);
      float e1 = (nib & 2u) ? 0.f : exp2f(acc[1]*LOG2E);
      float e2 = (nib & 4u) ? 0.f : exp2f(acc[2]*LOG2E);
      float e3 = (nib & 8u) ? 0.f : exp2f(acc[3]*LOG2E);
      lrun += (e0 + e1) + (e2 + e3);
    }
    sMB[(st<<6) + lane] = (uint16_t)bits;
  }
  lrun += __shfl_xor(lrun, 16, 64);
  lrun += __shfl_xor(lrun, 32, 64);
  const float invl = 1.0f / lrun;

  // ========== sweep 2: recompute, write attn, accumulate PV ==========
  f32x4 oacc[4];
#pragma unroll
  for (int n = 0; n < 4; n++) oacc[n] = (f32x4){0.f,0.f,0.f,0.f};

  auto compute2 = [&](int st){
    const int ks = st << 6;
    const char* sKc = lds + ((st&1) << 13);
    const char* sVc = lds + 16384 + ((st&1) << 13);
    const uint32_t bt = sMB[(st<<6) + lane];
#pragma unroll
    for (int c = 0; c < 2; c++){
#pragma unroll
      for (int t2 = 0; t2 < 2; t2++){
        const int kkk = c*2 + t2;
        const int r = (kkk<<4) + lq;
        short8v ka0 = *(const short8v*)(sKc + r*128 + (( g*16     ) ^ ((r & 7) << 4)));
        short8v ka1 = *(const short8v*)(sKc + r*128 + ((64 + g*16 ) ^ ((r & 7) << 4)));
        f32x4 acc = {0.f,0.f,0.f,0.f};
        acc = __builtin_amdgcn_mfma_f32_16x16x32_bf16(ka0, qf0, acc, 0,0,0);
        acc = __builtin_amdgcn_mfma_f32_16x16x32_bf16(ka1, qf1, acc, 0,0,0);
        uint32_t m4 = (bt >> (kkk*4)) & 15u;
        float p0 = (m4 & 1u) ? 0.f : exp2f(acc[0]*LOG2E) * invl;
        float p1 = (m4 & 2u) ? 0.f : exp2f(acc[1]*LOG2E) * invl;
        float p2 = (m4 & 4u) ? 0.f : exp2f(acc[2]*LOG2E) * invl;
        float p3 = (m4 & 8u) ? 0.f : exp2f(acc[3]*LOG2E) * invl;
        f32x4 stv = { p0, p1, p2, p3 };
        *(f32x4*)(attn + ((size_t)b*S_ + q0 + lq)*S_ + ks + kkk*16 + g*4) = stv;
        short4v pb = { f2bf(p0), f2bf(p1), f2bf(p2), f2bf(p3) };
        *(short4v*)(sP + lq*128 + ((t2*32 + g*8) ^ ((lq & 7) << 4))) = pb;
      }
      short8v pf = *(const short8v*)(sP + lq*128 + ((g*16) ^ ((lq & 7) << 4)));
#pragma unroll
      for (int n = 0; n < 4; n++){
        const int dr = lq + 16*n;
        short8v vf = *(const short8v*)(sVc + dr*128 + ((c*64 + g*16) ^ ((dr & 7) << 4)));
        oacc[n] = __builtin_amdgcn_mfma_f32_16x16x32_bf16(pf, vf, oacc[n], 0,0,0);
      }
    }
  };

  ISSUE2(0);
  WAIT0; BAR;            // stage-0 landed (no stores outstanding yet)
  ISSUE2(1);
  compute2(0);
  for (int st = 1; st < 32; ++st){
    WAIT4; BAR;          // drain next-stage K/V DMA; attn stores stay in flight
    if (st < 31) ISSUE2(st+1);
    compute2(st);
  }

  // epilogue: O[q = q0 + 4g + reg][d = lq + 16n]
#pragma unroll
  for (int n = 0; n < 4; n++){
#pragma unroll
    for (int r2 = 0; r2 < 4; r2++){
      outp[((size_t)b*S_ + q0 + 4*g + r2)*D_ + lq + 16*n] = oacc[n][r2];
    }
  }
}

extern "C" void kernel_launch(void* const* d_in, const int* in_sizes, int n_in,
                              void* d_out, int out_size, void* d_ws, size_t ws_size,
                              hipStream_t stream) {
  (void)in_sizes; (void)n_in; (void)out_size; (void)ws_size;
  const float* q    = (const float*)d_in[0];
  const float* k    = (const float*)d_in[1];
  const float* v    = (const float*)d_in[2];
  const int*   mask = (const int*)d_in[3];   // bool -> int32 per harness convention

  float* outp = (float*)d_out;
  float* attn = outp + (size_t)B_*S_*D_;     // outputs concatenated: output, attn

  short* qbuf = (short*)d_ws;                // 3 x 8.39MB bf16 scratch
  short* kbuf = qbuf + (size_t)B_*S_*D_;
  short* vbT  = kbuf + (size_t)B_*S_*D_;

  cvt_qk<<<4096, 256, 0, stream>>>(q, k, qbuf, kbuf);
  cvt_v<<<dim3(32, 32), 256, 0, stream>>>(v, vbT);
  attn_fused<<<dim3(32, 32), 256, 0, stream>>>(qbuf, kbuf, vbT, mask, outp, attn);
}